// Round 10
// baseline (238.120 us; speedup 1.0000x reference)
//
#include <hip/hip_runtime.h>
#include <hip/hip_bf16.h>

#define NN 50000
#define NE 600000
#define DD 128
#define LDSW 136
#define NB 196            // node buckets of 256: (NN+255)/256
#define BSH 8             // bucket shift (256 nodes/bucket)
#define EPB 2048          // edges per block in bucket passes
#define NBLK_AC ((NE + EPB - 1) / EPB)  // 293

typedef __bf16 bf16;
typedef __attribute__((ext_vector_type(8))) __bf16 bf16x8;
typedef __attribute__((ext_vector_type(4))) float f32x4;
typedef __attribute__((ext_vector_type(4))) unsigned int u32x4;
typedef __attribute__((ext_vector_type(4))) unsigned short u16x4;
typedef unsigned short u16;

__device__ __forceinline__ float bf_lo(unsigned int u) {
    return __builtin_bit_cast(float, u << 16);
}
__device__ __forceinline__ float bf_hi(unsigned int u) {
    return __builtin_bit_cast(float, u & 0xffff0000u);
}
__device__ __forceinline__ unsigned int bf_pack(float x, float y) {
    u16 a = __builtin_bit_cast(u16, (bf16)x);
    u16 b = __builtin_bit_cast(u16, (bf16)y);
    return (unsigned int)a | ((unsigned int)b << 16);
}

struct Ptr8 { const float* p[8]; };

__device__ __forceinline__ int edge_dst(const int* ei, int e, int f) {
    return f ? ei[2 * NE + 2 * e] : ei[NE + e];
}
__device__ __forceinline__ int edge_src(const int* ei, int e, int f) {
    return f ? ei[2 * e] : ei[e];
}

// ---------------- fused init: bcnt=0, bcur=0, detect, x->bf16, w->bf16^T ----------------
#define J1 (NN * DD / 4)         // xconv, 4 floats per id -> 1,600,000
#define J2 (J1 + 8 * DD * DD)    // wconv, 1 elem per id   -> 1,731,072

__global__ __launch_bounds__(256) void k_init(const float* __restrict__ x,
                                              u16* __restrict__ xb,
                                              Ptr8 ws, u16* __restrict__ wt,
                                              int* __restrict__ bcnt,
                                              int* __restrict__ bcur,
                                              const int* __restrict__ ei,
                                              int* __restrict__ flag) {
    int tid = threadIdx.x;
    if (blockIdx.x == 0) {
        if (tid == 0) flag[0] = 1;              // assume int64 layout
        __syncthreads();
        if (ei[2 * tid + 1] != 0) flag[0] = 0;  // any nonzero odd word => int32
    }
    int id = blockIdx.x * 256 + tid;
    if (id < NB) { bcnt[id] = 0; bcur[id] = 0; }
    if (id < J1) {
        f32x4 v = *(const f32x4*)(x + (size_t)id * 4);
        u16x4 o;
        o.x = __builtin_bit_cast(u16, (bf16)v.x);
        o.y = __builtin_bit_cast(u16, (bf16)v.y);
        o.z = __builtin_bit_cast(u16, (bf16)v.z);
        o.w = __builtin_bit_cast(u16, (bf16)v.w);
        *(u16x4*)(xb + (size_t)id * 4) = o;
    } else if (id < J2) {
        int i = id - J1;
        int m = i >> 14;
        int rem = i & 16383;
        int k = rem >> 7;
        int n = rem & 127;       // consecutive ids -> consecutive n (coalesced read)
        bf16 b = (bf16)ws.p[m][k * DD + n];
        wt[(size_t)m * DD * DD + n * DD + k] = __builtin_bit_cast(u16, b);
    }
}

// ---------------- CSR build, two-level bucket sort ----------------
// Pass A: per-bucket edge counts (LDS histogram, merged)
__global__ __launch_bounds__(256) void k_bcount(const int* __restrict__ ei,
                                                const int* __restrict__ flag,
                                                int* __restrict__ bcnt) {
    __shared__ int lh[NB];
    int tid = threadIdx.x;
    if (tid < NB) lh[tid] = 0;
    __syncthreads();
    int f = flag[0];
#pragma unroll
    for (int k = 0; k < 8; k++) {
        int e = blockIdx.x * EPB + k * 256 + tid;
        if (e < NE) {
            int d = edge_dst(ei, e, f);
            atomicAdd(&lh[d >> BSH], 1);
        }
    }
    __syncthreads();
    if (tid < NB && lh[tid] > 0) atomicAdd(&bcnt[tid], lh[tid]);
}

// Pass C: scatter packed (src | dlocal<<16) into contiguous bucket regions.
// Bucket base offsets computed locally (exclusive scan of bcnt); bcur holds
// bucket-relative cursors (zeroed in k_init).
__global__ __launch_bounds__(256) void k_bscatter(const int* __restrict__ ei,
                                                  const int* __restrict__ flag,
                                                  const int* __restrict__ bcnt,
                                                  int* __restrict__ bcur,
                                                  unsigned int* __restrict__ tmp) {
    __shared__ int lh[NB];
    __shared__ int gb[NB];
    __shared__ int sboff[NB];
    __shared__ int sm[4];
    int tid = threadIdx.x;
    if (tid < NB) lh[tid] = 0;
    __syncthreads();
    int f = flag[0];
    int src[8], dst[8], lp[8];
    bool val[8];
#pragma unroll
    for (int k = 0; k < 8; k++) {
        int e = blockIdx.x * EPB + k * 256 + tid;
        val[k] = (e < NE);
        if (val[k]) {
            src[k] = edge_src(ei, e, f);
            dst[k] = edge_dst(ei, e, f);
            lp[k] = atomicAdd(&lh[dst[k] >> BSH], 1);
        }
    }
    __syncthreads();
    // local exclusive scan of bcnt -> sboff
    {
        int lane = tid & 63, w = tid >> 6;
        int v = (tid < NB) ? bcnt[tid] : 0;
        int orig = v;
#pragma unroll
        for (int off = 1; off < 64; off <<= 1) {
            int t = __shfl_up(v, off);
            if (lane >= off) v += t;
        }
        if (lane == 63) sm[w] = v;
        __syncthreads();
        int add = 0;
        for (int k = 0; k < w; k++) add += sm[k];
        if (tid < NB) sboff[tid] = v - orig + add;
    }
    __syncthreads();
    if (tid < NB && lh[tid] > 0)
        gb[tid] = sboff[tid] + atomicAdd(&bcur[tid], lh[tid]);
    __syncthreads();
#pragma unroll
    for (int k = 0; k < 8; k++) {
        if (val[k]) {
            unsigned int pk = (unsigned)src[k] | ((unsigned)(dst[k] & 255) << 16);
            tmp[gb[dst[k] >> BSH] + lp[k]] = pk;
        }
    }
}

// Pass D: per-bucket local CSR (LDS count+scan+place) -> row_start + coalesced adj
__global__ __launch_bounds__(256) void k_build(const unsigned int* __restrict__ tmp,
                                               const int* __restrict__ bcnt,
                                               int* __restrict__ row_start,
                                               int* __restrict__ adj) {
    __shared__ int cnt[256];
    __shared__ int ccur[256];
    __shared__ int sm[4];
    int b = blockIdx.x, tid = threadIdx.x;
    int base = b << BSH;
    int lane = tid & 63, w = tid >> 6;
    cnt[tid] = 0;
    // s = sum(bcnt[0..b-1]) via block reduce
    int v = (tid < b) ? bcnt[tid] : 0;
#pragma unroll
    for (int off = 1; off < 64; off <<= 1) v += __shfl_xor(v, off);
    if (lane == 0) sm[w] = v;
    __syncthreads();
    int s = sm[0] + sm[1] + sm[2] + sm[3];
    int e = s + bcnt[b];
    for (int i = s + tid; i < e; i += 256) {
        atomicAdd(&cnt[tmp[i] >> 16], 1);
    }
    __syncthreads();
    int v2 = cnt[tid];
    int orig = v2;
#pragma unroll
    for (int off = 1; off < 64; off <<= 1) {
        int t = __shfl_up(v2, off);
        if (lane >= off) v2 += t;
    }
    if (lane == 63) sm[w] = v2;
    __syncthreads();
    int add = 0;
    for (int k = 0; k < w; k++) add += sm[k];
    int ex = s + (v2 - orig) + add;   // global adj base for node base+tid
    ccur[tid] = ex;
    if (base + tid < NN) row_start[base + tid] = ex;
    if (b == 0 && tid == 0) row_start[NN] = NE;
    __syncthreads();
    for (int i = s + tid; i < e; i += 256) {
        unsigned int pk = tmp[i];
        int p = atomicAdd(&ccur[pk >> 16], 1);
        adj[p] = (int)(pk & 0xffffu);
    }
}

// ---------------- aggregation: 4 nodes/wave, 16 lanes x 16B per row, 8-deep ILP ----------------
__global__ __launch_bounds__(256) void k_agg(const u16* __restrict__ xb,
                                             const int* __restrict__ row_start,
                                             const int* __restrict__ adj,
                                             u16* __restrict__ out) {
    int gid = blockIdx.x * blockDim.x + threadIdx.x;
    int wave = gid >> 6, lane = gid & 63;
    int grp = lane >> 4, l = lane & 15;
    int node = wave * 4 + grp;
    if (node >= NN) return;
    const u32x4* base = (const u32x4*)xb;  // 16 x dwordx4 per row
    u32x4 sv = base[(size_t)node * 16 + l];
    float af[8], bf[8];
#pragma unroll
    for (int j = 0; j < 4; j++) {
        af[2 * j] = bf_lo(sv[j]); af[2 * j + 1] = bf_hi(sv[j]);
        bf[2 * j] = 0.f; bf[2 * j + 1] = 0.f;
    }
    int s = row_start[node], e = row_start[node + 1];
    int i = s;
    for (; i + 7 < e; i += 8) {
        u32x4 t0 = base[(size_t)adj[i] * 16 + l];
        u32x4 t1 = base[(size_t)adj[i + 1] * 16 + l];
        u32x4 t2 = base[(size_t)adj[i + 2] * 16 + l];
        u32x4 t3 = base[(size_t)adj[i + 3] * 16 + l];
        u32x4 t4 = base[(size_t)adj[i + 4] * 16 + l];
        u32x4 t5 = base[(size_t)adj[i + 5] * 16 + l];
        u32x4 t6 = base[(size_t)adj[i + 6] * 16 + l];
        u32x4 t7 = base[(size_t)adj[i + 7] * 16 + l];
#pragma unroll
        for (int j = 0; j < 4; j++) {
            af[2 * j]     += (bf_lo(t0[j]) + bf_lo(t1[j])) + (bf_lo(t2[j]) + bf_lo(t3[j]));
            af[2 * j + 1] += (bf_hi(t0[j]) + bf_hi(t1[j])) + (bf_hi(t2[j]) + bf_hi(t3[j]));
            bf[2 * j]     += (bf_lo(t4[j]) + bf_lo(t5[j])) + (bf_lo(t6[j]) + bf_lo(t7[j]));
            bf[2 * j + 1] += (bf_hi(t4[j]) + bf_hi(t5[j])) + (bf_hi(t6[j]) + bf_hi(t7[j]));
        }
    }
    for (; i + 3 < e; i += 4) {
        u32x4 t0 = base[(size_t)adj[i] * 16 + l];
        u32x4 t1 = base[(size_t)adj[i + 1] * 16 + l];
        u32x4 t2 = base[(size_t)adj[i + 2] * 16 + l];
        u32x4 t3 = base[(size_t)adj[i + 3] * 16 + l];
#pragma unroll
        for (int j = 0; j < 4; j++) {
            af[2 * j]     += bf_lo(t0[j]) + bf_lo(t1[j]);
            af[2 * j + 1] += bf_hi(t0[j]) + bf_hi(t1[j]);
            bf[2 * j]     += bf_lo(t2[j]) + bf_lo(t3[j]);
            bf[2 * j + 1] += bf_hi(t2[j]) + bf_hi(t3[j]);
        }
    }
    for (; i < e; i++) {
        u32x4 t = base[(size_t)adj[i] * 16 + l];
#pragma unroll
        for (int j = 0; j < 4; j++) { af[2 * j] += bf_lo(t[j]); af[2 * j + 1] += bf_hi(t[j]); }
    }
    u32x4 o;
#pragma unroll
    for (int j = 0; j < 4; j++) o[j] = bf_pack(af[2 * j] + bf[2 * j], af[2 * j + 1] + bf[2 * j + 1]);
    ((u32x4*)out)[(size_t)node * 16 + l] = o;
}

// ---------------- fused MLP (+LN+relu), 64-node tile, 2 waves x 32 rows ----------------
template <bool LN, bool B16OUT>
__global__ __launch_bounds__(128) void k_mlp(const u16* __restrict__ hin,
                                             const u16* __restrict__ w1t,
                                             const float* __restrict__ b1,
                                             const u16* __restrict__ w2t,
                                             const float* __restrict__ b2,
                                             const float* __restrict__ g,
                                             const float* __restrict__ bta,
                                             void* __restrict__ hout) {
    __shared__ u16 lds[64 * LDSW];
    const int tid = threadIdx.x;
    const int wv = tid >> 6, lane = tid & 63;
    const int l15 = lane & 15, l4 = lane >> 4;
    const int tile0 = blockIdx.x * 64;

    // stage 64 rows (1024 x 16B slots, 8 iters of 128 threads)
#pragma unroll
    for (int it = 0; it < 8; ++it) {
        int slot = tid + it * 128;
        int row = slot >> 4, c16 = slot & 15;
        u32x4 v = {0u, 0u, 0u, 0u};
        int grow = tile0 + row;
        if (grow < NN) v = *(const u32x4*)(hin + (size_t)grow * DD + c16 * 8);
        *(u32x4*)&lds[row * LDSW + c16 * 8] = v;
    }
    __syncthreads();

    float b1c[8], b2c[8], gc[8], bc[8];
#pragma unroll
    for (int c = 0; c < 8; c++) {
        int col = c * 16 + l15;
        b1c[c] = b1[col];
        b2c[c] = b2[col];
        if (LN) { gc[c] = g[col]; bc[c] = bta[col]; }
    }

    f32x4 acc[2][8];
#pragma unroll
    for (int r = 0; r < 2; r++)
#pragma unroll
        for (int c = 0; c < 8; c++) acc[r][c] = (f32x4){0.f, 0.f, 0.f, 0.f};

    const int rowbase = wv * 32;

    // GEMM1: h1 = relu(A @ W1 + b1)  (each B-fragment feeds 2 MFMAs)
#pragma unroll
    for (int ks = 0; ks < 4; ++ks) {
        bf16x8 a0 = __builtin_bit_cast(bf16x8,
            *(const u32x4*)&lds[(rowbase + l15) * LDSW + ks * 32 + l4 * 8]);
        bf16x8 a1 = __builtin_bit_cast(bf16x8,
            *(const u32x4*)&lds[(rowbase + 16 + l15) * LDSW + ks * 32 + l4 * 8]);
#pragma unroll
        for (int c = 0; c < 8; c++) {
            bf16x8 b = __builtin_bit_cast(bf16x8,
                *(const u32x4*)(w1t + (size_t)(c * 16 + l15) * DD + ks * 32 + l4 * 8));
            acc[0][c] = __builtin_amdgcn_mfma_f32_16x16x32_bf16(a0, b, acc[0][c], 0, 0, 0);
            acc[1][c] = __builtin_amdgcn_mfma_f32_16x16x32_bf16(a1, b, acc[1][c], 0, 0, 0);
        }
    }

    // h1 -> LDS (bf16, relu); rows rowbase..rowbase+31 are wave-private: no barrier
#pragma unroll
    for (int r = 0; r < 2; r++) {
#pragma unroll
        for (int c = 0; c < 8; c++) {
            int col = c * 16 + l15;
#pragma unroll
            for (int j = 0; j < 4; j++) {
                float v = acc[r][c][j] + b1c[c];
                v = v > 0.f ? v : 0.f;
                bf16 b = (bf16)v;
                int row = rowbase + r * 16 + l4 * 4 + j;
                lds[row * LDSW + col] = __builtin_bit_cast(u16, b);
            }
        }
    }

#pragma unroll
    for (int r = 0; r < 2; r++)
#pragma unroll
        for (int c = 0; c < 8; c++) acc[r][c] = (f32x4){0.f, 0.f, 0.f, 0.f};

    // GEMM2: h2 = h1 @ W2 + b2 (reads only this wave's rows)
#pragma unroll
    for (int ks = 0; ks < 4; ++ks) {
        bf16x8 a0 = __builtin_bit_cast(bf16x8,
            *(const u32x4*)&lds[(rowbase + l15) * LDSW + ks * 32 + l4 * 8]);
        bf16x8 a1 = __builtin_bit_cast(bf16x8,
            *(const u32x4*)&lds[(rowbase + 16 + l15) * LDSW + ks * 32 + l4 * 8]);
#pragma unroll
        for (int c = 0; c < 8; c++) {
            bf16x8 b = __builtin_bit_cast(bf16x8,
                *(const u32x4*)(w2t + (size_t)(c * 16 + l15) * DD + ks * 32 + l4 * 8));
            acc[0][c] = __builtin_amdgcn_mfma_f32_16x16x32_bf16(a0, b, acc[0][c], 0, 0, 0);
            acc[1][c] = __builtin_amdgcn_mfma_f32_16x16x32_bf16(a1, b, acc[1][c], 0, 0, 0);
        }
    }

    // epilogue: +b2, optional LN+relu, store
#pragma unroll
    for (int r = 0; r < 2; r++) {
        float vals[8][4];
#pragma unroll
        for (int c = 0; c < 8; c++)
#pragma unroll
            for (int j = 0; j < 4; j++) vals[c][j] = acc[r][c][j] + b2c[c];

        if (LN) {
            float s[4], q[4];
#pragma unroll
            for (int j = 0; j < 4; j++) {
                s[j] = 0.f; q[j] = 0.f;
#pragma unroll
                for (int c = 0; c < 8; c++) {
                    s[j] += vals[c][j];
                    q[j] += vals[c][j] * vals[c][j];
                }
            }
#pragma unroll
            for (int m = 1; m <= 8; m <<= 1) {
#pragma unroll
                for (int j = 0; j < 4; j++) {
                    s[j] += __shfl_xor(s[j], m);
                    q[j] += __shfl_xor(q[j], m);
                }
            }
#pragma unroll
            for (int j = 0; j < 4; j++) {
                float mu = s[j] * (1.f / 128.f);
                float var = q[j] * (1.f / 128.f) - mu * mu;
                float rs = rsqrtf(var + 1e-5f);
#pragma unroll
                for (int c = 0; c < 8; c++) {
                    float v = (vals[c][j] - mu) * rs * gc[c] + bc[c];
                    vals[c][j] = v > 0.f ? v : 0.f;
                }
            }
        }

        if (B16OUT) {
            // write bf16 back into this wave's own LDS rows (no barrier needed)
#pragma unroll
            for (int c = 0; c < 8; c++) {
                int col = c * 16 + l15;
#pragma unroll
                for (int j = 0; j < 4; j++) {
                    int row = rowbase + r * 16 + l4 * 4 + j;
                    lds[row * LDSW + col] =
                        __builtin_bit_cast(u16, (bf16)vals[c][j]);
                }
            }
        } else {
#pragma unroll
            for (int c = 0; c < 8; c++) {
                int col = c * 16 + l15;
#pragma unroll
                for (int j = 0; j < 4; j++) {
                    int row = tile0 + rowbase + r * 16 + l4 * 4 + j;
                    if (row < NN)
                        ((float*)hout)[(size_t)row * DD + col] = vals[c][j];
                }
            }
        }
    }

    if (B16OUT) {
        // vectorized copy-out of this wave's 32 rows: 8 rounds x (ds_read_b128 + dwordx4 store)
#pragma unroll
        for (int it = 0; it < 8; ++it) {
            int slot = it * 64 + lane;          // 0..511
            int row = rowbase + (slot >> 4);    // 32 rows
            int c16 = slot & 15;
            u32x4 v = *(const u32x4*)&lds[row * LDSW + c16 * 8];
            int grow = tile0 + row;
            if (grow < NN)
                *(u32x4*)((u16*)hout + (size_t)grow * DD + c16 * 8) = v;
        }
    }
}

// ---------------- launch ----------------
extern "C" void kernel_launch(void* const* d_in, const int* in_sizes, int n_in,
                              void* d_out, int out_size, void* d_ws, size_t ws_size,
                              hipStream_t stream) {
    const float* x = (const float*)d_in[0];
    const int* ei = (const int*)d_in[1];
    const float* w1[4]; const float* b1[4]; const float* w2[4]; const float* b2[4];
    for (int i = 0; i < 4; i++) {
        w1[i] = (const float*)d_in[2 + 4 * i];
        b1[i] = (const float*)d_in[3 + 4 * i];
        w2[i] = (const float*)d_in[4 + 4 * i];
        b2[i] = (const float*)d_in[5 + 4 * i];
    }
    const float* g[3]; const float* bt[3];
    for (int i = 0; i < 3; i++) {
        g[i] = (const float*)d_in[18 + 2 * i];
        bt[i] = (const float*)d_in[19 + 2 * i];
    }

    char* ws = (char*)d_ws;
    size_t off = 0;
    auto alloc = [&](size_t bytes) -> char* {
        char* p = ws + off;
        off = (off + bytes + 255) & ~(size_t)255;
        return p;
    };
    int* flag          = (int*)alloc(4);
    int* row_start     = (int*)alloc((NN + 1) * 4);
    int* bcnt          = (int*)alloc(NB * 4);
    int* bcur          = (int*)alloc(NB * 4);
    int* adj           = (int*)alloc(NE * 4);
    unsigned int* tmp  = (unsigned int*)alloc((size_t)NE * 4);
    u16* wt            = (u16*)alloc((size_t)8 * DD * DD * 2);
    u16* xb            = (u16*)alloc((size_t)NN * DD * 2);
    u16* hbf           = (u16*)alloc((size_t)NN * DD * 2);
    u16* hA            = (u16*)alloc((size_t)NN * DD * 2);
    u16* hB            = (u16*)alloc((size_t)NN * DD * 2);

    Ptr8 p8;
    for (int i = 0; i < 4; i++) {
        p8.p[2 * i] = w1[i];
        p8.p[2 * i + 1] = w2[i];
    }

    k_init<<<(J2 + 255) / 256, 256, 0, stream>>>(x, xb, p8, wt, bcnt, bcur, ei, flag);
    k_bcount<<<NBLK_AC, 256, 0, stream>>>(ei, flag, bcnt);
    k_bscatter<<<NBLK_AC, 256, 0, stream>>>(ei, flag, bcnt, bcur, tmp);
    k_build<<<NB, 256, 0, stream>>>(tmp, bcnt, row_start, adj);

    const int mgrid = (NN + 63) / 64;  // 782
    const u16* hin = xb;
    for (int i = 0; i < 4; i++) {
        k_agg<<<(NN / 4 * 64) / 256, 256, 0, stream>>>(hin, row_start, adj, hbf);
        const u16* w1ti = wt + (size_t)(2 * i) * DD * DD;
        const u16* w2ti = wt + (size_t)(2 * i + 1) * DD * DD;
        if (i < 3) {
            u16* outp = (i & 1) ? hB : hA;
            k_mlp<true, true><<<mgrid, 128, 0, stream>>>(
                hbf, w1ti, b1[i], w2ti, b2[i], g[i], bt[i], outp);
            hin = outp;
        } else {
            k_mlp<false, false><<<mgrid, 128, 0, stream>>>(
                hbf, w1ti, b1[i], w2ti, b2[i], nullptr, nullptr, d_out);
        }
    }
}

// Round 11
// 229.285 us; speedup vs baseline: 1.0385x; 1.0385x over previous
//
#include <hip/hip_runtime.h>
#include <hip/hip_bf16.h>

#define NN 50000
#define NE 600000
#define DD 128
#define LDSW 136
#define NB 196            // node buckets of 256: (NN+255)/256
#define BSH 8             // bucket shift (256 nodes/bucket)
#define BSTR 4096         // fixed tmp stride per bucket (max bucket ~3280, 19 sigma margin)
#define EPB 2048          // edges per block in scatter pass
#define NBLK_AC ((NE + EPB - 1) / EPB)  // 293

typedef __bf16 bf16;
typedef __attribute__((ext_vector_type(8))) __bf16 bf16x8;
typedef __attribute__((ext_vector_type(4))) float f32x4;
typedef __attribute__((ext_vector_type(4))) unsigned int u32x4;
typedef __attribute__((ext_vector_type(4))) unsigned short u16x4;
typedef unsigned short u16;

__device__ __forceinline__ float bf_lo(unsigned int u) {
    return __builtin_bit_cast(float, u << 16);
}
__device__ __forceinline__ float bf_hi(unsigned int u) {
    return __builtin_bit_cast(float, u & 0xffff0000u);
}
__device__ __forceinline__ unsigned int bf_pack(float x, float y) {
    u16 a = __builtin_bit_cast(u16, (bf16)x);
    u16 b = __builtin_bit_cast(u16, (bf16)y);
    return (unsigned int)a | ((unsigned int)b << 16);
}

struct Ptr8 { const float* p[8]; };

__device__ __forceinline__ int edge_dst(const int* ei, int e, int f) {
    return f ? ei[2 * NE + 2 * e] : ei[NE + e];
}
__device__ __forceinline__ int edge_src(const int* ei, int e, int f) {
    return f ? ei[2 * e] : ei[e];
}

// ---------------- fused init: bcnt=0, detect, x->bf16, w->bf16^T ----------------
#define J1 (NN * DD / 4)         // xconv, 4 floats per id -> 1,600,000
#define J2 (J1 + 8 * DD * DD)    // wconv, 1 elem per id   -> 1,731,072

__global__ __launch_bounds__(256) void k_init(const float* __restrict__ x,
                                              u16* __restrict__ xb,
                                              Ptr8 ws, u16* __restrict__ wt,
                                              int* __restrict__ bcnt,
                                              const int* __restrict__ ei,
                                              int* __restrict__ flag) {
    int tid = threadIdx.x;
    if (blockIdx.x == 0) {
        if (tid == 0) flag[0] = 1;              // assume int64 layout
        __syncthreads();
        if (ei[2 * tid + 1] != 0) flag[0] = 0;  // any nonzero odd word => int32
    }
    int id = blockIdx.x * 256 + tid;
    if (id < NB) bcnt[id] = 0;
    if (id < J1) {
        f32x4 v = *(const f32x4*)(x + (size_t)id * 4);
        u16x4 o;
        o.x = __builtin_bit_cast(u16, (bf16)v.x);
        o.y = __builtin_bit_cast(u16, (bf16)v.y);
        o.z = __builtin_bit_cast(u16, (bf16)v.z);
        o.w = __builtin_bit_cast(u16, (bf16)v.w);
        *(u16x4*)(xb + (size_t)id * 4) = o;
    } else if (id < J2) {
        int i = id - J1;
        int m = i >> 14;
        int rem = i & 16383;
        int k = rem >> 7;
        int n = rem & 127;       // consecutive ids -> consecutive n (coalesced read)
        bf16 b = (bf16)ws.p[m][k * DD + n];
        wt[(size_t)m * DD * DD + n * DD + k] = __builtin_bit_cast(u16, b);
    }
}

// ---------------- CSR build: single-pass scatter into fixed-stride buckets ----------------
// packed entry: src (16b) | dst_local (8b) << 16. bcnt acts as cursor AND final count.
__global__ __launch_bounds__(256) void k_scatter(const int* __restrict__ ei,
                                                 const int* __restrict__ flag,
                                                 int* __restrict__ bcnt,
                                                 unsigned int* __restrict__ tmp) {
    __shared__ int lh[NB];
    __shared__ int gb[NB];
    int tid = threadIdx.x;
    if (tid < NB) lh[tid] = 0;
    __syncthreads();
    int f = flag[0];
    int src[8], dst[8], lp[8];
    bool val[8];
#pragma unroll
    for (int k = 0; k < 8; k++) {
        int e = blockIdx.x * EPB + k * 256 + tid;
        val[k] = (e < NE);
        if (val[k]) {
            src[k] = edge_src(ei, e, f);
            dst[k] = edge_dst(ei, e, f);
            lp[k] = atomicAdd(&lh[dst[k] >> BSH], 1);
        }
    }
    __syncthreads();
    if (tid < NB && lh[tid] > 0) gb[tid] = atomicAdd(&bcnt[tid], lh[tid]);
    __syncthreads();
#pragma unroll
    for (int k = 0; k < 8; k++) {
        if (val[k]) {
            int bkt = dst[k] >> BSH;
            unsigned int pk = (unsigned)src[k] | ((unsigned)(dst[k] & 255) << 16);
            tmp[(size_t)bkt * BSTR + gb[bkt] + lp[k]] = pk;
        }
    }
}

// Pass D: per-bucket local CSR (LDS count+scan+place) -> row_start + coalesced adj
__global__ __launch_bounds__(256) void k_build(const unsigned int* __restrict__ tmp,
                                               const int* __restrict__ bcnt,
                                               int* __restrict__ row_start,
                                               int* __restrict__ adj) {
    __shared__ int cnt[256];
    __shared__ int ccur[256];
    __shared__ int sm[4];
    int b = blockIdx.x, tid = threadIdx.x;
    int base = b << BSH;
    int lane = tid & 63, w = tid >> 6;
    cnt[tid] = 0;
    // G = sum(bcnt[0..b-1]) via block reduce
    int v = (tid < b) ? bcnt[tid] : 0;
#pragma unroll
    for (int off = 1; off < 64; off <<= 1) v += __shfl_xor(v, off);
    if (lane == 0) sm[w] = v;
    __syncthreads();
    int G = sm[0] + sm[1] + sm[2] + sm[3];
    int n = bcnt[b];
    size_t ts = (size_t)b * BSTR;
    for (int i = tid; i < n; i += 256) {
        atomicAdd(&cnt[tmp[ts + i] >> 16], 1);
    }
    __syncthreads();
    int v2 = cnt[tid];
    int orig = v2;
#pragma unroll
    for (int off = 1; off < 64; off <<= 1) {
        int t = __shfl_up(v2, off);
        if (lane >= off) v2 += t;
    }
    if (lane == 63) sm[w] = v2;
    __syncthreads();
    int add = 0;
    for (int k = 0; k < w; k++) add += sm[k];
    int ex = G + (v2 - orig) + add;   // global adj base for node base+tid
    ccur[tid] = ex;
    if (base + tid < NN) row_start[base + tid] = ex;
    if (b == 0 && tid == 0) row_start[NN] = NE;
    __syncthreads();
    for (int i = tid; i < n; i += 256) {
        unsigned int pk = tmp[ts + i];
        int p = atomicAdd(&ccur[pk >> 16], 1);
        adj[p] = (int)(pk & 0xffffu);
    }
}

// ---------------- aggregation: 4 nodes/wave, 16 lanes x 16B per row, 8-deep ILP ----------------
__global__ __launch_bounds__(256) void k_agg(const u16* __restrict__ xb,
                                             const int* __restrict__ row_start,
                                             const int* __restrict__ adj,
                                             u16* __restrict__ out) {
    int gid = blockIdx.x * blockDim.x + threadIdx.x;
    int wave = gid >> 6, lane = gid & 63;
    int grp = lane >> 4, l = lane & 15;
    int node = wave * 4 + grp;
    if (node >= NN) return;
    const u32x4* base = (const u32x4*)xb;  // 16 x dwordx4 per row
    u32x4 sv = base[(size_t)node * 16 + l];
    float af[8], bf[8];
#pragma unroll
    for (int j = 0; j < 4; j++) {
        af[2 * j] = bf_lo(sv[j]); af[2 * j + 1] = bf_hi(sv[j]);
        bf[2 * j] = 0.f; bf[2 * j + 1] = 0.f;
    }
    int s = row_start[node], e = row_start[node + 1];
    int i = s;
    for (; i + 7 < e; i += 8) {
        u32x4 t0 = base[(size_t)adj[i] * 16 + l];
        u32x4 t1 = base[(size_t)adj[i + 1] * 16 + l];
        u32x4 t2 = base[(size_t)adj[i + 2] * 16 + l];
        u32x4 t3 = base[(size_t)adj[i + 3] * 16 + l];
        u32x4 t4 = base[(size_t)adj[i + 4] * 16 + l];
        u32x4 t5 = base[(size_t)adj[i + 5] * 16 + l];
        u32x4 t6 = base[(size_t)adj[i + 6] * 16 + l];
        u32x4 t7 = base[(size_t)adj[i + 7] * 16 + l];
#pragma unroll
        for (int j = 0; j < 4; j++) {
            af[2 * j]     += (bf_lo(t0[j]) + bf_lo(t1[j])) + (bf_lo(t2[j]) + bf_lo(t3[j]));
            af[2 * j + 1] += (bf_hi(t0[j]) + bf_hi(t1[j])) + (bf_hi(t2[j]) + bf_hi(t3[j]));
            bf[2 * j]     += (bf_lo(t4[j]) + bf_lo(t5[j])) + (bf_lo(t6[j]) + bf_lo(t7[j]));
            bf[2 * j + 1] += (bf_hi(t4[j]) + bf_hi(t5[j])) + (bf_hi(t6[j]) + bf_hi(t7[j]));
        }
    }
    for (; i + 3 < e; i += 4) {
        u32x4 t0 = base[(size_t)adj[i] * 16 + l];
        u32x4 t1 = base[(size_t)adj[i + 1] * 16 + l];
        u32x4 t2 = base[(size_t)adj[i + 2] * 16 + l];
        u32x4 t3 = base[(size_t)adj[i + 3] * 16 + l];
#pragma unroll
        for (int j = 0; j < 4; j++) {
            af[2 * j]     += bf_lo(t0[j]) + bf_lo(t1[j]);
            af[2 * j + 1] += bf_hi(t0[j]) + bf_hi(t1[j]);
            bf[2 * j]     += bf_lo(t2[j]) + bf_lo(t3[j]);
            bf[2 * j + 1] += bf_hi(t2[j]) + bf_hi(t3[j]);
        }
    }
    for (; i < e; i++) {
        u32x4 t = base[(size_t)adj[i] * 16 + l];
#pragma unroll
        for (int j = 0; j < 4; j++) { af[2 * j] += bf_lo(t[j]); af[2 * j + 1] += bf_hi(t[j]); }
    }
    u32x4 o;
#pragma unroll
    for (int j = 0; j < 4; j++) o[j] = bf_pack(af[2 * j] + bf[2 * j], af[2 * j + 1] + bf[2 * j + 1]);
    ((u32x4*)out)[(size_t)node * 16 + l] = o;
}

// ---------------- fused MLP (+LN+relu), 64-node tile, ONE wave x 64 rows (B-reuse 4) ----------------
template <bool LN, bool B16OUT>
__global__ __launch_bounds__(64) void k_mlp(const u16* __restrict__ hin,
                                            const u16* __restrict__ w1t,
                                            const float* __restrict__ b1,
                                            const u16* __restrict__ w2t,
                                            const float* __restrict__ b2,
                                            const float* __restrict__ g,
                                            const float* __restrict__ bta,
                                            void* __restrict__ hout) {
    __shared__ u16 lds[64 * LDSW];
    const int lane = threadIdx.x;
    const int l15 = lane & 15, l4 = lane >> 4;
    const int tile0 = blockIdx.x * 64;

    // stage 64 rows (1024 x 16B slots, 16 iters of 64 lanes)
#pragma unroll
    for (int it = 0; it < 16; ++it) {
        int slot = lane + it * 64;
        int row = slot >> 4, c16 = slot & 15;
        u32x4 v = {0u, 0u, 0u, 0u};
        int grow = tile0 + row;
        if (grow < NN) v = *(const u32x4*)(hin + (size_t)grow * DD + c16 * 8);
        *(u32x4*)&lds[row * LDSW + c16 * 8] = v;
    }
    __syncthreads();

    float b1c[8], b2c[8], gc[8], bc[8];
#pragma unroll
    for (int c = 0; c < 8; c++) {
        int col = c * 16 + l15;
        b1c[c] = b1[col];
        b2c[c] = b2[col];
        if (LN) { gc[c] = g[col]; bc[c] = bta[col]; }
    }

    f32x4 acc[4][8];
#pragma unroll
    for (int r = 0; r < 4; r++)
#pragma unroll
        for (int c = 0; c < 8; c++) acc[r][c] = (f32x4){0.f, 0.f, 0.f, 0.f};

    // GEMM1: h1 = relu(A @ W1 + b1)  (each B-fragment feeds 4 MFMAs)
#pragma unroll
    for (int ks = 0; ks < 4; ++ks) {
        bf16x8 a0 = __builtin_bit_cast(bf16x8,
            *(const u32x4*)&lds[(l15) * LDSW + ks * 32 + l4 * 8]);
        bf16x8 a1 = __builtin_bit_cast(bf16x8,
            *(const u32x4*)&lds[(16 + l15) * LDSW + ks * 32 + l4 * 8]);
        bf16x8 a2 = __builtin_bit_cast(bf16x8,
            *(const u32x4*)&lds[(32 + l15) * LDSW + ks * 32 + l4 * 8]);
        bf16x8 a3 = __builtin_bit_cast(bf16x8,
            *(const u32x4*)&lds[(48 + l15) * LDSW + ks * 32 + l4 * 8]);
#pragma unroll
        for (int c = 0; c < 8; c++) {
            bf16x8 b = __builtin_bit_cast(bf16x8,
                *(const u32x4*)(w1t + (size_t)(c * 16 + l15) * DD + ks * 32 + l4 * 8));
            acc[0][c] = __builtin_amdgcn_mfma_f32_16x16x32_bf16(a0, b, acc[0][c], 0, 0, 0);
            acc[1][c] = __builtin_amdgcn_mfma_f32_16x16x32_bf16(a1, b, acc[1][c], 0, 0, 0);
            acc[2][c] = __builtin_amdgcn_mfma_f32_16x16x32_bf16(a2, b, acc[2][c], 0, 0, 0);
            acc[3][c] = __builtin_amdgcn_mfma_f32_16x16x32_bf16(a3, b, acc[3][c], 0, 0, 0);
        }
    }

    // h1 -> LDS (bf16, relu); single wave: rows private, same-lane RAW handled by waitcnt
#pragma unroll
    for (int r = 0; r < 4; r++) {
#pragma unroll
        for (int c = 0; c < 8; c++) {
            int col = c * 16 + l15;
#pragma unroll
            for (int j = 0; j < 4; j++) {
                float v = acc[r][c][j] + b1c[c];
                v = v > 0.f ? v : 0.f;
                bf16 b = (bf16)v;
                int row = r * 16 + l4 * 4 + j;
                lds[row * LDSW + col] = __builtin_bit_cast(u16, b);
            }
        }
    }

#pragma unroll
    for (int r = 0; r < 4; r++)
#pragma unroll
        for (int c = 0; c < 8; c++) acc[r][c] = (f32x4){0.f, 0.f, 0.f, 0.f};

    // GEMM2: h2 = h1 @ W2 + b2
#pragma unroll
    for (int ks = 0; ks < 4; ++ks) {
        bf16x8 a0 = __builtin_bit_cast(bf16x8,
            *(const u32x4*)&lds[(l15) * LDSW + ks * 32 + l4 * 8]);
        bf16x8 a1 = __builtin_bit_cast(bf16x8,
            *(const u32x4*)&lds[(16 + l15) * LDSW + ks * 32 + l4 * 8]);
        bf16x8 a2 = __builtin_bit_cast(bf16x8,
            *(const u32x4*)&lds[(32 + l15) * LDSW + ks * 32 + l4 * 8]);
        bf16x8 a3 = __builtin_bit_cast(bf16x8,
            *(const u32x4*)&lds[(48 + l15) * LDSW + ks * 32 + l4 * 8]);
#pragma unroll
        for (int c = 0; c < 8; c++) {
            bf16x8 b = __builtin_bit_cast(bf16x8,
                *(const u32x4*)(w2t + (size_t)(c * 16 + l15) * DD + ks * 32 + l4 * 8));
            acc[0][c] = __builtin_amdgcn_mfma_f32_16x16x32_bf16(a0, b, acc[0][c], 0, 0, 0);
            acc[1][c] = __builtin_amdgcn_mfma_f32_16x16x32_bf16(a1, b, acc[1][c], 0, 0, 0);
            acc[2][c] = __builtin_amdgcn_mfma_f32_16x16x32_bf16(a2, b, acc[2][c], 0, 0, 0);
            acc[3][c] = __builtin_amdgcn_mfma_f32_16x16x32_bf16(a3, b, acc[3][c], 0, 0, 0);
        }
    }

    // epilogue: +b2, optional LN+relu, store
#pragma unroll
    for (int r = 0; r < 4; r++) {
        float vals[8][4];
#pragma unroll
        for (int c = 0; c < 8; c++)
#pragma unroll
            for (int j = 0; j < 4; j++) vals[c][j] = acc[r][c][j] + b2c[c];

        if (LN) {
            float s[4], q[4];
#pragma unroll
            for (int j = 0; j < 4; j++) {
                s[j] = 0.f; q[j] = 0.f;
#pragma unroll
                for (int c = 0; c < 8; c++) {
                    s[j] += vals[c][j];
                    q[j] += vals[c][j] * vals[c][j];
                }
            }
#pragma unroll
            for (int m = 1; m <= 8; m <<= 1) {
#pragma unroll
                for (int j = 0; j < 4; j++) {
                    s[j] += __shfl_xor(s[j], m);
                    q[j] += __shfl_xor(q[j], m);
                }
            }
#pragma unroll
            for (int j = 0; j < 4; j++) {
                float mu = s[j] * (1.f / 128.f);
                float var = q[j] * (1.f / 128.f) - mu * mu;
                float rs = rsqrtf(var + 1e-5f);
#pragma unroll
                for (int c = 0; c < 8; c++) {
                    float v = (vals[c][j] - mu) * rs * gc[c] + bc[c];
                    vals[c][j] = v > 0.f ? v : 0.f;
                }
            }
        }

        if (B16OUT) {
            // write bf16 back into this wave's own LDS rows
#pragma unroll
            for (int c = 0; c < 8; c++) {
                int col = c * 16 + l15;
#pragma unroll
                for (int j = 0; j < 4; j++) {
                    int row = r * 16 + l4 * 4 + j;
                    lds[row * LDSW + col] =
                        __builtin_bit_cast(u16, (bf16)vals[c][j]);
                }
            }
        } else {
#pragma unroll
            for (int c = 0; c < 8; c++) {
                int col = c * 16 + l15;
#pragma unroll
                for (int j = 0; j < 4; j++) {
                    int row = tile0 + r * 16 + l4 * 4 + j;
                    if (row < NN)
                        ((float*)hout)[(size_t)row * DD + col] = vals[c][j];
                }
            }
        }
    }

    if (B16OUT) {
        // vectorized copy-out: 16 rounds x (ds_read_b128 + dwordx4 store)
#pragma unroll
        for (int it = 0; it < 16; ++it) {
            int slot = it * 64 + lane;          // 0..1023
            int row = slot >> 4;                // 64 rows
            int c16 = slot & 15;
            u32x4 v = *(const u32x4*)&lds[row * LDSW + c16 * 8];
            int grow = tile0 + row;
            if (grow < NN)
                *(u32x4*)((u16*)hout + (size_t)grow * DD + c16 * 8) = v;
        }
    }
}

// ---------------- launch ----------------
extern "C" void kernel_launch(void* const* d_in, const int* in_sizes, int n_in,
                              void* d_out, int out_size, void* d_ws, size_t ws_size,
                              hipStream_t stream) {
    const float* x = (const float*)d_in[0];
    const int* ei = (const int*)d_in[1];
    const float* w1[4]; const float* b1[4]; const float* w2[4]; const float* b2[4];
    for (int i = 0; i < 4; i++) {
        w1[i] = (const float*)d_in[2 + 4 * i];
        b1[i] = (const float*)d_in[3 + 4 * i];
        w2[i] = (const float*)d_in[4 + 4 * i];
        b2[i] = (const float*)d_in[5 + 4 * i];
    }
    const float* g[3]; const float* bt[3];
    for (int i = 0; i < 3; i++) {
        g[i] = (const float*)d_in[18 + 2 * i];
        bt[i] = (const float*)d_in[19 + 2 * i];
    }

    char* ws = (char*)d_ws;
    size_t off = 0;
    auto alloc = [&](size_t bytes) -> char* {
        char* p = ws + off;
        off = (off + bytes + 255) & ~(size_t)255;
        return p;
    };
    int* flag          = (int*)alloc(4);
    int* row_start     = (int*)alloc((NN + 1) * 4);
    int* bcnt          = (int*)alloc(NB * 4);
    int* adj           = (int*)alloc(NE * 4);
    unsigned int* tmp  = (unsigned int*)alloc((size_t)NB * BSTR * 4);
    u16* wt            = (u16*)alloc((size_t)8 * DD * DD * 2);
    u16* xb            = (u16*)alloc((size_t)NN * DD * 2);
    u16* hbf           = (u16*)alloc((size_t)NN * DD * 2);
    u16* hA            = (u16*)alloc((size_t)NN * DD * 2);
    u16* hB            = (u16*)alloc((size_t)NN * DD * 2);

    Ptr8 p8;
    for (int i = 0; i < 4; i++) {
        p8.p[2 * i] = w1[i];
        p8.p[2 * i + 1] = w2[i];
    }

    k_init<<<(J2 + 255) / 256, 256, 0, stream>>>(x, xb, p8, wt, bcnt, ei, flag);
    k_scatter<<<NBLK_AC, 256, 0, stream>>>(ei, flag, bcnt, tmp);
    k_build<<<NB, 256, 0, stream>>>(tmp, bcnt, row_start, adj);

    const int mgrid = (NN + 63) / 64;  // 782
    const u16* hin = xb;
    for (int i = 0; i < 4; i++) {
        k_agg<<<(NN / 4 * 64) / 256, 256, 0, stream>>>(hin, row_start, adj, hbf);
        const u16* w1ti = wt + (size_t)(2 * i) * DD * DD;
        const u16* w2ti = wt + (size_t)(2 * i + 1) * DD * DD;
        if (i < 3) {
            u16* outp = (i & 1) ? hB : hA;
            k_mlp<true, true><<<mgrid, 64, 0, stream>>>(
                hbf, w1ti, b1[i], w2ti, b2[i], g[i], bt[i], outp);
            hin = outp;
        } else {
            k_mlp<false, false><<<mgrid, 64, 0, stream>>>(
                hbf, w1ti, b1[i], w2ti, b2[i], nullptr, nullptr, d_out);
        }
    }
}